// Round 6
// baseline (11055.685 us; speedup 1.0000x reference)
//
#include <hip/hip_runtime.h>

#define TT 500
#define S1 (52*128*8)   // xb1 slot elems (416 k-rows = 52 octets)
#define S2 (50*128*8)   // xb2/xb3 slot elems (400 k-rows)
#define SW (8*128*8)    // wring slot elems (64 k-rows)

// dynamic LDS (floats)
#define G_P   0          // 128*68 partial-exchange           [GRU2/3, OUT]
#define G_HP  8704       // 16*128 persistent fp32 h-state    [GRU roles]
// ATTN (32-batch slice per WG)
#define A2_AL  0         // 30*33
#define A2_PH  992       // 50*33
#define A2_WR  2656      // 64*33
#define A2_KAP 4784      // 10*32 persistent kappa
#define A2_CID 5104      // 32*50 ints
#define A2_BC  6704      // 30
#define SMEMF 26720

typedef __attribute__((ext_vector_type(8))) short short8;
typedef __attribute__((ext_vector_type(4))) short short4v;
typedef __attribute__((ext_vector_type(4))) float f32x4;
typedef unsigned long long u64;

#define MFMA16(A,B,C) __builtin_amdgcn_mfma_f32_16x16x32_bf16((A),(B),(C),0,0,0)

struct Params {
  const float* seq; const int* cid;
  const float *Wi1,*Wh1,*bi1,*bh1;
  const float *Wc,*bc;
  const float *Wi2,*Wh2,*bi2,*bh2;
  const float *Wi3,*Wh3,*bi3,*bh3;
  const float *Wl,*bl;
  float* out;
  unsigned* bar;                           // 83 flags, 64B stride
  unsigned short *xb1, *xb2, *xb3, *wr;    // bf16 payload, swizzled [k>>3][n][k&7]
};

__device__ __forceinline__ short rneb(float f) {
  union { float f; unsigned u; } c; c.f = f;
  unsigned u = c.u;
  return (short)((u + 0x7FFFu + ((u >> 16) & 1u)) >> 16);
}
__device__ __forceinline__ float sigm(float x) { return 1.f / (1.f + expf(-x)); }

// Cross-WG payload: agent-scope relaxed atomics (sc1: bypass non-coherent L2,
// served by the shared coherence point). Proven correct in rounds 3-5.
__device__ __forceinline__ short8 ld8(const unsigned short* b, int o, int n) {
  const u64* q = (const u64*)(b + (size_t)(o*128 + n)*8);
  union { u64 u[2]; short8 s; } c;
  c.u[0] = __hip_atomic_load(q,     __ATOMIC_RELAXED, __HIP_MEMORY_SCOPE_AGENT);
  c.u[1] = __hip_atomic_load(q + 1, __ATOMIC_RELAXED, __HIP_MEMORY_SCOPE_AGENT);
  return c.s;
}
__device__ __forceinline__ void st8(unsigned short* b, int o, int n, short8 v) {
  u64* q = (u64*)(b + (size_t)(o*128 + n)*8);
  union { short8 s; u64 u[2]; } c; c.s = v;
  __hip_atomic_store(q,     c.u[0], __ATOMIC_RELAXED, __HIP_MEMORY_SCOPE_AGENT);
  __hip_atomic_store(q + 1, c.u[1], __ATOMIC_RELAXED, __HIP_MEMORY_SCOPE_AGENT);
}
__device__ __forceinline__ void st4(unsigned short* addr, short4v v) {
  union { short4v s; u64 u; } c; c.s = v;
  __hip_atomic_store((u64*)addr, c.u, __ATOMIC_RELAXED, __HIP_MEMORY_SCOPE_AGENT);
}
__device__ __forceinline__ short8 relu8(short8 v) { short8 s = v >> 15; return v & ~s; }

// P2P wait: wave 0 polls up to 2 flags per lane; others park at the barrier.
// Lane's condition: F[idx] >= t + off. Wave-min of slack decides.
__device__ __forceinline__ void pollwait(unsigned* F, int t,
                                         int i0, int o0, int i1, int o1, int tid) {
  if (tid < 64) {
    for (;;) {
      int s = 0x7fffffff;
      if (i0 >= 0) {
        int f = (int)__hip_atomic_load(F + i0, __ATOMIC_RELAXED, __HIP_MEMORY_SCOPE_AGENT);
        s = f - (t + o0);
      }
      if (i1 >= 0) {
        int f = (int)__hip_atomic_load(F + i1, __ATOMIC_RELAXED, __HIP_MEMORY_SCOPE_AGENT);
        int s1 = f - (t + o1); s = s < s1 ? s : s1;
      }
#pragma unroll
      for (int off = 32; off; off >>= 1) {
        int o = __shfl_xor(s, off, 64);
        s = s < o ? s : o;
      }
      if (s >= 0) break;
      __builtin_amdgcn_s_sleep(1);
    }
  }
  __syncthreads();
}

// Publish progress: drain own memory ops, WG-converge, then flag-store.
__device__ __forceinline__ void publish(unsigned* F, int wg, unsigned v, int tid) {
  __builtin_amdgcn_s_waitcnt(0);
  __syncthreads();
  if (tid == 0)
    __hip_atomic_store(F + wg*16, v, __ATOMIC_RELAXED, __HIP_MEMORY_SCOPE_AGENT);
}

__device__ __forceinline__ void writeX(const Params& p, int tn, int tid) {
  if (tn >= TT) return;
  unsigned short* dst = p.xb1 + (size_t)(tn & 7) * S1;
  if (tid < 128) {
    int n = tid;
    const float* s = p.seq + ((size_t)tn*128 + n)*3;
    short8 v = { rneb(s[0]), rneb(s[1]), rneb(s[2]), 0,0,0,0,0 };
    st8(dst, 50, n, v);
  } else if (tid < 256) {
    int n = tid - 128;
    short8 z = {0,0,0,0,0,0,0,0};
    st8(dst, 51, n, z);
  }
}

__global__ __launch_bounds__(512, 2) void hwnet_kernel(Params p)
{
  extern __shared__ float sm[];
  const int wg = blockIdx.x, tid = threadIdx.x;
  const int lane = tid & 63, wv = tid >> 6;
  const int quad = lane >> 4, col = lane & 15;

  int role, hj = 0, q = 0, ab = 0;
  if      (wg < 25) { role = 0; hj = wg; }        // GRU1
  else if (wg < 50) { role = 1; hj = wg - 25; }   // GRU2
  else if (wg < 75) { role = 2; hj = wg - 50; }   // GRU3
  else if (wg < 79) { role = 3; q  = wg - 75; }   // OUT
  else              { role = 4; ab = wg - 79; }   // ATTN (batch quarter)

  const int kh = wv >> 2, npair = wv & 3;
  const f32x4 z4 = {0.f, 0.f, 0.f, 0.f};

  short8 wfa[42];
  short8 wfx = {0,0,0,0,0,0,0,0};

  // ---------------- one-time preload of weight fragments into registers ----------------
  if (role == 1 || role == 2) {
    const float* Wi = (role == 1) ? p.Wi2 : p.Wi3;
    const float* Wh = (role == 1) ? p.Wh2 : p.Wh3;
#pragma unroll
    for (int rt = 0; rt < 3; ++rt) {
      const int grow = rt*400 + hj*16 + col;
      const float* wi = Wi + (size_t)grow * 464;
      const float* wh = Wh + (size_t)grow * 400;
      if (kh == 0) {
#pragma unroll
        for (int ktl = 0; ktl < 14; ++ktl) {
          short8 f;
#pragma unroll
          for (int j = 0; j < 8; ++j) {
            int k = ktl*32 + quad*8 + j;                 // <448, all in Wi range
            f[j] = rneb(wi[k]);
          }
          wfa[rt*14 + ktl] = f;
        }
      } else {
#pragma unroll
        for (int ktl = 0; ktl < 13; ++ktl) {
          short8 f;
#pragma unroll
          for (int j = 0; j < 8; ++j) {
            int k = (14 + ktl)*32 + quad*8 + j;
            float v = (k < 464) ? wi[k] : wh[k - 464];
            if (rt == 2 && ktl == 0 && k < 464) v = 0.f; // n-gate: hi(B)-part only
            f[j] = rneb(v);
          }
          wfa[rt*14 + ktl] = f;
        }
      }
    }
    if (kh == 1) {  // n-gate lo(A)-part of boundary ktile 14
      const int grow = 2*400 + hj*16 + col;
      const float* wi = Wi + (size_t)grow * 464;
      short8 f;
#pragma unroll
      for (int j = 0; j < 8; ++j) {
        int k = 14*32 + quad*8 + j;
        f[j] = rneb((k < 464) ? wi[k] : 0.f);
      }
      wfx = f;
    }
  } else if (role == 0) {
#pragma unroll
    for (int rt = 0; rt < 3; ++rt) {
      const int grow = rt*400 + hj*16 + col;
      const float* whr = p.Wh1 + (size_t)grow * 400;
      const float* wir = p.Wi1 + (size_t)grow * 67;
#pragma unroll
      for (int ktl = 0; ktl < 13; ++ktl) {
        short8 f;
#pragma unroll
        for (int j = 0; j < 8; ++j) {
          int k = ktl*32 + quad*8 + j;
          float v = 0.f;
          if (k < 400) v = whr[k];
          else if (k < 403) v = wir[k - 400];
          if (rt == 2 && ktl == 12 && k >= 400) v = 0.f; // n-gate: lo(B)-part only
          f[j] = rneb(v);
        }
        wfa[rt*14 + ktl] = f;
      }
    }
    { // n-gate hi(A = x-cols) part of boundary ktile 12
      const int grow = 2*400 + hj*16 + col;
      const float* wir = p.Wi1 + (size_t)grow * 67;
      short8 f;
#pragma unroll
      for (int j = 0; j < 8; ++j) {
        int k = 12*32 + quad*8 + j;
        f[j] = rneb((k >= 400 && k < 403) ? wir[k - 400] : 0.f);
      }
      wfx = f;
    }
  } else if (role == 3) {
#pragma unroll
    for (int rt = 0; rt < 2; ++rt) {
      const int grow = q*32 + rt*16 + col;
      const float* wl = p.Wl + (size_t)grow * 1264;
#pragma unroll
      for (int ktl = 0; ktl < 20; ++ktl) {
        short8 f;
#pragma unroll
        for (int j = 0; j < 8; ++j) {
          int k = (kh*20 + ktl)*32 + quad*8 + j;
          f[j] = rneb((grow < 121 && k < 1264) ? wl[k] : 0.f);
        }
        wfa[rt*20 + ktl] = f;
      }
    }
  } else { // ATTN
#pragma unroll
    for (int rt = 0; rt < 2; ++rt) {
      const int grow = rt*16 + col;
      const float* wc = p.Wc + (size_t)grow * 400;
#pragma unroll
      for (int ktl = 0; ktl < 13; ++ktl) {
        short8 f;
#pragma unroll
        for (int j = 0; j < 8; ++j) {
          int k = ktl*32 + quad*8 + j;
          f[j] = rneb((grow < 30 && k < 400) ? wc[k] : 0.f);
        }
        wfa[rt*13 + ktl] = f;
      }
    }
    int* cidl = (int*)(sm + A2_CID);
    for (int i = tid; i < 32*50; i += 512) {
      const int b = i / 50, u = i - 50*b;
      cidl[i] = p.cid[(size_t)(ab*32 + b)*50 + u] & 63;
    }
    for (int i = tid; i < 320; i += 512) sm[A2_KAP + i] = 0.f;
    for (int i = tid; i < 30; i += 512) sm[A2_BC + i] = p.bc[i];
  }

  // biases into registers
  float bR[4], bZ[4], bNi[4], bNh[4], blr[8];
  if (role < 3) {
    const float* bi = role == 0 ? p.bi1 : role == 1 ? p.bi2 : p.bi3;
    const float* bh = role == 0 ? p.bh1 : role == 1 ? p.bh2 : p.bh3;
#pragma unroll
    for (int r = 0; r < 4; ++r) {
      int row = hj*16 + quad*4 + r;
      bR[r]  = bi[row] + bh[row];
      bZ[r]  = bi[400 + row] + bh[400 + row];
      bNi[r] = bi[800 + row];
      bNh[r] = bh[800 + row];
    }
    for (int i = tid; i < 2048; i += 512) sm[G_HP + i] = 0.f;
  }
  if (role == 3) {
#pragma unroll
    for (int rt = 0; rt < 2; ++rt)
#pragma unroll
      for (int r = 0; r < 4; ++r) {
        int row = q*32 + rt*16 + quad*4 + r;
        blr[rt*4 + r] = (row < 121) ? p.bl[row] : 0.f;
      }
  }

  // zero t=-1 ring content (slot 0 holds h(-1)) via sc1 stores
  if (role == 0) {
    u64* b0 = (u64*)(p.xb1 + (size_t)hj*2*128*8);
    for (int i = tid; i < 512; i += 512)
      __hip_atomic_store(b0 + i, 0ull, __ATOMIC_RELAXED, __HIP_MEMORY_SCOPE_AGENT);
    if (hj == 0) writeX(p, 0, tid);
  } else if (role == 1) {
    u64* b0 = (u64*)(p.xb2 + (size_t)hj*2*128*8);
    for (int i = tid; i < 512; i += 512)
      __hip_atomic_store(b0 + i, 0ull, __ATOMIC_RELAXED, __HIP_MEMORY_SCOPE_AGENT);
  } else if (role == 2) {
    u64* b0 = (u64*)(p.xb3 + (size_t)hj*2*128*8);
    for (int i = tid; i < 512; i += 512)
      __hip_atomic_store(b0 + i, 0ull, __ATOMIC_RELAXED, __HIP_MEMORY_SCOPE_AGENT);
  }

  // ---------------- build p2p dependency table (lane -> up to 2 flag checks) ----------------
  // F semantics: F[w] = 1 after init; = t+2 after completing local step t.
  // {base,count,offset}: lane waits for F[idx] >= t + offset.
  int i0 = -1, o0 = 0, i1 = -1, o1 = 0;
  {
    int eb[5], ec[5], eo[5], ne = 0;
    if (role == 0) {        // GRU1: self h1(t-1); anti-overwrite h1/x(t-8) readers
      eb[0]=0;  ec[0]=25; eo[0]=1;
      eb[1]=25; ec[1]=25; eo[1]=-5;
      eb[2]=75; ec[2]=4;  eo[2]=-5;
      eb[3]=79; ec[3]=4;  eo[3]=-5; ne = 4;
    } else if (role == 1) { // GRU2: h1(t), w(t), self h2(t-1); overwrite readers G3/OUT
      eb[0]=0;  ec[0]=25; eo[0]=2;
      eb[1]=79; ec[1]=4;  eo[1]=2;
      eb[2]=25; ec[2]=25; eo[2]=1;
      eb[3]=50; ec[3]=25; eo[3]=-5;
      eb[4]=75; ec[4]=4;  eo[4]=-5; ne = 5;
    } else if (role == 2) { // GRU3: h2(t), w(t), self h3(t-1); overwrite reader OUT
      eb[0]=25; ec[0]=25; eo[0]=2;
      eb[1]=79; ec[1]=4;  eo[1]=2;
      eb[2]=50; ec[2]=25; eo[2]=1;
      eb[3]=75; ec[3]=4;  eo[3]=-5; ne = 4;
    } else if (role == 3) { // OUT: h1,h2,h3,w at t
      eb[0]=0;  ec[0]=25; eo[0]=2;
      eb[1]=25; ec[1]=25; eo[1]=2;
      eb[2]=50; ec[2]=25; eo[2]=2;
      eb[3]=79; ec[3]=4;  eo[3]=2; ne = 4;
    } else {                // ATTN: h1(t); anti-overwrite w(t-8) readers
      eb[0]=0;  ec[0]=25; eo[0]=2;
      eb[1]=25; ec[1]=25; eo[1]=-6;
      eb[2]=50; ec[2]=25; eo[2]=-6;
      eb[3]=75; ec[3]=4;  eo[3]=-6; ne = 4;
    }
    if (tid < 64) {
      int pos = 0;
      for (int e = 0; e < ne; ++e)
        for (int c = 0; c < ec[e]; ++c, ++pos) {
          if ((pos & 63) == tid) {
            if (pos < 64) { i0 = (eb[e] + c)*16; o0 = eo[e]; }
            else          { i1 = (eb[e] + c)*16; o1 = eo[e]; }
          }
        }
    }
  }

  publish(p.bar, wg, 1u, tid);   // init done

  // ---------------- elastic p2p-pipelined main loop ----------------
  for (int t = 0; t < TT; ++t) {
    pollwait(p.bar, t, i0, o0, i1, o1, tid);

    if (role == 1 || role == 2) {                      // GRU2 / GRU3
      const unsigned short* srcRelu = (role == 1 ? p.xb1 : p.xb2) + (size_t)((t+1)&7) * (role == 1 ? S1 : S2);
      const unsigned short* wrs     = p.wr + (size_t)(t&7) * SW;
      const unsigned short* srcOwn  = (role == 1 ? p.xb2 : p.xb3) + (size_t)(t&7) * S2;
      unsigned short*       dstW    = (role == 1 ? p.xb2 : p.xb3) + (size_t)((t+1)&7) * S2;
      f32x4 aR[2] = {z4, z4}, aZ[2] = {z4, z4}, aN[2] = {z4, z4}, aNB[2] = {z4, z4};
#pragma unroll
      for (int nt = 0; nt < 2; ++nt) {
        const int n = npair*32 + nt*16 + col;
        if (kh == 0) {
#pragma unroll
          for (int c2 = 0; c2 < 2; ++c2) {
            short8 bf[7];
#pragma unroll
            for (int i = 0; i < 7; ++i) {
              int o = (c2*7 + i)*4 + quad;
              bf[i] = (o < 50) ? relu8(ld8(srcRelu, o, n)) : ld8(wrs, o - 50, n);
            }
#pragma unroll
            for (int i = 0; i < 7; ++i) {
              int kt = c2*7 + i;
              aR[nt] = MFMA16(wfa[kt],      bf[i], aR[nt]);
              aZ[nt] = MFMA16(wfa[14 + kt], bf[i], aZ[nt]);
              aN[nt] = MFMA16(wfa[28 + kt], bf[i], aN[nt]);
            }
          }
        } else {
#pragma unroll
          for (int c2 = 0; c2 < 2; ++c2) {
            const int cn = c2 ? 6 : 7;
            short8 bf[7];
#pragma unroll
            for (int i = 0; i < 7; ++i) if (i < cn) {
              int o = (14 + c2*7 + i)*4 + quad;
              bf[i] = (o < 58) ? ld8(wrs, o - 50, n) : ld8(srcOwn, o - 58, n);
            }
#pragma unroll
            for (int i = 0; i < 7; ++i) if (i < cn) {
              int ktl = c2*7 + i;
              aR[nt]  = MFMA16(wfa[ktl],      bf[i], aR[nt]);
              aZ[nt]  = MFMA16(wfa[14 + ktl], bf[i], aZ[nt]);
              aNB[nt] = MFMA16(wfa[28 + ktl], bf[i], aNB[nt]);
              if (ktl == 0) aN[nt] = MFMA16(wfx, bf[i], aN[nt]);
            }
          }
        }
      }
      float* P = sm + G_P;
      if (kh == 1) {
#pragma unroll
        for (int nt = 0; nt < 2; ++nt) {
          int cg = npair*32 + nt*16 + col;
          float* pc = P + cg*68 + quad*4;
          *(f32x4*)(pc)      = aR[nt];
          *(f32x4*)(pc + 16) = aZ[nt];
          *(f32x4*)(pc + 32) = aN[nt];
          *(f32x4*)(pc + 48) = aNB[nt];
        }
      }
      __syncthreads();
      if (kh == 0) {
#pragma unroll
        for (int nt = 0; nt < 2; ++nt) {
          int cg = npair*32 + nt*16 + col;
          const float* pc = P + cg*68 + quad*4;
          f32x4 pR  = *(const f32x4*)(pc);
          f32x4 pZ  = *(const f32x4*)(pc + 16);
          f32x4 pNA = *(const f32x4*)(pc + 32);
          f32x4 pNB = *(const f32x4*)(pc + 48);
          short hq[4];
#pragma unroll
          for (int r = 0; r < 4; ++r) {
            float R  = aR[nt][r] + pR[r] + bR[r];
            float Z  = aZ[nt][r] + pZ[r] + bZ[r];
            float NA = aN[nt][r] + pNA[r] + bNi[r];
            float NB = pNB[r] + bNh[r];
            float rg = sigm(R), zg = sigm(Z);
            float ng = tanhf(NA + rg*NB);
            int m = quad*4 + r;
            float hpv = sm[G_HP + m*128 + cg];
            float h = (1.f - zg)*ng + zg*hpv;
            sm[G_HP + m*128 + cg] = h;
            hq[r] = rneb(h);
          }
          short4v hv = {hq[0], hq[1], hq[2], hq[3]};
          st4(dstW + (size_t)((hj*2 + (quad >> 1))*128 + cg)*8 + (quad & 1)*4, hv);
        }
      }
    } else if (role == 0) {                            // GRU1
      const unsigned short* src = p.xb1 + (size_t)(t&7) * S1;
      unsigned short* dstW = p.xb1 + (size_t)((t+1)&7) * S1;
      f32x4 aR = z4, aZ = z4, aNA = z4, aNB = z4;
      const int n = wv*16 + col;
#pragma unroll
      for (int c2 = 0; c2 < 2; ++c2) {
        const int cn = c2 ? 6 : 7;
        short8 bf[7];
#pragma unroll
        for (int i = 0; i < 7; ++i) if (i < cn) bf[i] = ld8(src, (c2*7 + i)*4 + quad, n);
#pragma unroll
        for (int i = 0; i < 7; ++i) if (i < cn) {
          int kt = c2*7 + i;
          aR  = MFMA16(wfa[kt],      bf[i], aR);
          aZ  = MFMA16(wfa[14 + kt], bf[i], aZ);
          aNB = MFMA16(wfa[28 + kt], bf[i], aNB);
          if (kt == 12) aNA = MFMA16(wfx, bf[i], aNA);
        }
      }
      short hq[4];
#pragma unroll
      for (int r = 0; r < 4; ++r) {
        float rg = sigm(aR[r] + bR[r]);
        float zg = sigm(aZ[r] + bZ[r]);
        float ng = tanhf(aNA[r] + bNi[r] + rg*(aNB[r] + bNh[r]));
        int m = quad*4 + r;
        float hpv = sm[G_HP + m*128 + n];
        float h = (1.f - zg)*ng + zg*hpv;
        sm[G_HP + m*128 + n] = h;
        hq[r] = rneb(h);
      }
      short4v hv = {hq[0], hq[1], hq[2], hq[3]};
      st4(dstW + (size_t)((hj*2 + (quad >> 1))*128 + n)*8 + (quad & 1)*4, hv);
      if (hj == 0) writeX(p, t + 1, tid);
    } else if (role == 3) {                            // OUT
      const unsigned short* s3p = p.xb3 + (size_t)((t+1)&7) * S2;
      const unsigned short* s2p = p.xb2 + (size_t)((t+1)&7) * S2;
      const unsigned short* s1p = p.xb1 + (size_t)((t+1)&7) * S1;
      const unsigned short* wrs = p.wr + (size_t)(t&7) * SW;
      f32x4 a0[2] = {z4, z4}, a1[2] = {z4, z4};
#pragma unroll
      for (int nt = 0; nt < 2; ++nt) {
        const int n = npair*32 + nt*16 + col;
#pragma unroll
        for (int c2 = 0; c2 < 2; ++c2) {
          short8 bf[10];
#pragma unroll
          for (int i = 0; i < 10; ++i) {
            int o = (kh*20 + c2*10 + i)*4 + quad;
            short8 v;
            if      (o < 50)  v = relu8(ld8(s3p, o, n));
            else if (o < 100) v = relu8(ld8(s2p, o - 50, n));
            else if (o < 150) v = relu8(ld8(s1p, o - 100, n));
            else if (o < 158) v = ld8(wrs, o - 150, n);
            else { short8 zz = {0,0,0,0,0,0,0,0}; v = zz; }
            bf[i] = v;
          }
#pragma unroll
          for (int i = 0; i < 10; ++i) {
            int ktl = c2*10 + i;
            a0[nt] = MFMA16(wfa[ktl],      bf[i], a0[nt]);
            a1[nt] = MFMA16(wfa[20 + ktl], bf[i], a1[nt]);
          }
        }
      }
      float* P = sm + G_P;
      if (kh == 1) {
#pragma unroll
        for (int nt = 0; nt < 2; ++nt) {
          int cg = npair*32 + nt*16 + col;
          float* pc = P + cg*68 + quad*4;
          *(f32x4*)(pc)      = a0[nt];
          *(f32x4*)(pc + 16) = a1[nt];
        }
      }
      __syncthreads();
      if (kh == 0) {
#pragma unroll
        for (int nt = 0; nt < 2; ++nt) {
          int cg = npair*32 + nt*16 + col;
          const float* pc = P + cg*68 + quad*4;
          f32x4 p0 = *(const f32x4*)(pc);
          f32x4 p1 = *(const f32x4*)(pc + 16);
#pragma unroll
          for (int rt = 0; rt < 2; ++rt)
#pragma unroll
            for (int r = 0; r < 4; ++r) {
              int row = q*32 + rt*16 + quad*4 + r;
              float v = (rt ? a1[nt][r] + p1[r] : a0[nt][r] + p0[r]) + blr[rt*4 + r];
              if (row < 121) p.out[((size_t)cg*TT + t)*121 + row] = v;
            }
        }
      }
    } else {                                           // ATTN (batch quarter ab)
      const unsigned short* src = p.xb1 + (size_t)((t+1)&7) * S1;
      unsigned short* wdst = p.wr + (size_t)(t&7) * SW;
      f32x4 a0 = z4, a1 = z4;
      if (wv < 2) {
        const int n = ab*32 + wv*16 + col;
#pragma unroll
        for (int c2 = 0; c2 < 2; ++c2) {
          const int cn = c2 ? 6 : 7;
          short8 bf[7];
#pragma unroll
          for (int i = 0; i < 7; ++i) if (i < cn) bf[i] = ld8(src, (c2*7 + i)*4 + quad, n);
#pragma unroll
          for (int i = 0; i < 7; ++i) if (i < cn) {
            int kt = c2*7 + i;
            a0 = MFMA16(wfa[kt],      bf[i], a0);
            a1 = MFMA16(wfa[13 + kt], bf[i], a1);
          }
        }
#pragma unroll
        for (int rt = 0; rt < 2; ++rt)
#pragma unroll
          for (int r = 0; r < 4; ++r) {
            int row = rt*16 + quad*4 + r;
            if (row < 30) sm[A2_AL + row*33 + wv*16 + col] = (rt ? a1[r] : a0[r]);
          }
      }
      __syncthreads();
      for (int idx = tid; idx < 30*32; idx += 512) {
        int l = idx >> 5, b = idx & 31;
        float v = expf(sm[A2_AL + l*33 + b] + sm[A2_BC + l]);
        if (l >= 20) { float kk = sm[A2_KAP + (l-20)*32 + b] + v; sm[A2_KAP + (l-20)*32 + b] = kk; v = kk; }
        sm[A2_AL + l*33 + b] = v;
      }
      __syncthreads();
      for (int idx = tid; idx < 50*32; idx += 512) {
        int u = idx >> 5, b = idx & 31;
        float ph = 0.f;
#pragma unroll
        for (int j = 0; j < 10; ++j) {
          float al = sm[A2_AL + j*33 + b];
          float be = sm[A2_AL + (10 + j)*33 + b];
          float ka = sm[A2_AL + (20 + j)*33 + b];
          float d = ka - (float)u;
          ph += al * expf(-be*d*d);
        }
        sm[A2_PH + u*33 + b] = ph;
      }
      __syncthreads();
      for (int i = tid; i < 64*33; i += 512) sm[A2_WR + i] = 0.f;
      __syncthreads();
      if (tid < 32) {
        int b = tid;
        const int* cidl = (const int*)(sm + A2_CID);
        for (int u = 0; u < 50; ++u)
          sm[A2_WR + cidl[b*50 + u]*33 + b] += sm[A2_PH + u*33 + b];
      }
      __syncthreads();
      if (tid < 256) {
        int o = tid >> 5, b = tid & 31;
        short8 v;
#pragma unroll
        for (int e = 0; e < 8; ++e) v[e] = rneb(sm[A2_WR + (o*8 + e)*33 + b]);
        st8(wdst, o, ab*32 + b, v);
      }
    }

    publish(p.bar, wg, (unsigned)(t + 2), tid);
  }
}

extern "C" void kernel_launch(void* const* d_in, const int* in_sizes, int n_in,
                              void* d_out, int out_size, void* d_ws, size_t ws_size,
                              hipStream_t stream)
{
  (void)in_sizes; (void)n_in; (void)out_size; (void)ws_size;
  Params p;
  p.seq = (const float*)d_in[0];
  p.cid = (const int*)  d_in[1];
  p.Wi1 = (const float*)d_in[2];  p.Wh1 = (const float*)d_in[3];
  p.bi1 = (const float*)d_in[4];  p.bh1 = (const float*)d_in[5];
  p.Wc  = (const float*)d_in[6];  p.bc  = (const float*)d_in[7];
  p.Wi2 = (const float*)d_in[8];  p.Wh2 = (const float*)d_in[9];
  p.bi2 = (const float*)d_in[10]; p.bh2 = (const float*)d_in[11];
  p.Wi3 = (const float*)d_in[12]; p.Wh3 = (const float*)d_in[13];
  p.bi3 = (const float*)d_in[14]; p.bh3 = (const float*)d_in[15];
  p.Wl  = (const float*)d_in[16]; p.bl  = (const float*)d_in[17];
  p.out = (float*)d_out;

  char* ws = (char*)d_ws;
  p.bar = (unsigned*)ws;                      ws += 8192;   // 83 flags * 64B
  p.xb1 = (unsigned short*)ws;                ws += (size_t)8 * S1 * 2;
  p.xb2 = (unsigned short*)ws;                ws += (size_t)8 * S2 * 2;
  p.xb3 = (unsigned short*)ws;                ws += (size_t)8 * S2 * 2;
  p.wr  = (unsigned short*)ws;                ws += (size_t)8 * SW * 2;

  hipMemsetAsync(d_ws, 0, 8192, stream);      // zero progress flags

  hipFuncSetAttribute(reinterpret_cast<const void*>(hwnet_kernel),
                      hipFuncAttributeMaxDynamicSharedMemorySize, SMEMF * 4);

  void* args[] = { &p };
  hipLaunchCooperativeKernel(reinterpret_cast<void*>(hwnet_kernel),
                             dim3(83), dim3(512), args, SMEMF * 4, stream);
}